// Round 13
// baseline (325.356 us; speedup 1.0000x reference)
//
#include <hip/hip_runtime.h>

#define BS 16
#define NH 16
#define LQ 4096
#define DH 32

constexpr size_t OUT_ELEMS = (size_t)BS * NH * LQ * DH;   // 33,554,432
constexpr int HDE = NH * DH * DH;           // 16384

// global -> LDS direct copy, 16 B per lane. dst is the WAVE-UNIFORM base;
// HW writes dst + lane*16. src is per-lane.
__device__ __forceinline__ void async_cp16(float* dst, const float* src) {
    __builtin_amdgcn_global_load_lds(
        (const __attribute__((address_space(1))) void*)src,
        (__attribute__((address_space(3))) void*)dst, 16, 0, 0);
}

__device__ __forceinline__ void fma4(float4& a, float s, const float4& v) {
    a.x = fmaf(s, v.x, a.x);
    a.y = fmaf(s, v.y, a.y);
    a.z = fmaf(s, v.z, a.z);
    a.w = fmaf(s, v.w, a.w);
}

// ---------------- Kernel A: partial K@V ----------------
// R12 diagnosis: VALU floor is 13.7us (2048 v_fma_f32/thread), measured
// VALUBusy 19% at occupancy 28% -> issue-starved. The compiler sinks the V
// loads into the st loop (VGPR 68, reg-optimal); each st stalls ~500cyc on
// L2/L3 with only ~2 waves/SIMD to cover. FIX: __launch_bounds__(256,7) --
// VGPR cap 73 >= achieved 68, LDS 18432B fits 8 blocks -> up to 7 blocks/CU
// (28 waves). TLP covers the sunk-load latency; VALU util should 3-4x.
template<int NCH>
__global__ __launch_bounds__(256, 7) void kv_partial(const float* __restrict__ k,
                                                     const float* __restrict__ v,
                                                     float* __restrict__ part) {
    __shared__ float lds[4608];             // K[32][128] swz (4096) / reduce 4x1152
    const int tid = threadIdx.x;
    const int w   = tid >> 6;
    const int l   = tid & 63;
    const int nsplit = 32 / NCH;
    const int p  = blockIdx.x % nsplit;
    const int bh = blockIdx.x / nsplit;

    const int tw = tid & 31;
    const int sp = tid >> 5;                // 0..7
    const int dg = tw >> 3;                 // 0..3
    const int eg = tw & 7;                  // 0..7
    const int d0 = dg << 3;
    const int e0 = eg << 2;

    const float* kb = k + (size_t)bh * DH * LQ;
    const float* vb = v + (size_t)bh * LQ * DH;

    // K gll source constants: instr j covers rows {2j,2j+1}; lane l -> row
    // d = 2j + (l>>5), stored chunk cs = l&31 holds source chunk cs ^ ((j>>2)&3)
    size_t ksrc[4];
#pragma unroll
    for (int jj = 0; jj < 4; ++jj) {
        const int j = (w << 2) | jj;
        const int d = (j << 1) + (l >> 5);
        const int csrc = (l & 31) ^ ((j >> 2) & 3);
        ksrc[jj] = (size_t)d * LQ + (csrc << 2);
    }

    float4 acc[8];
#pragma unroll
    for (int i = 0; i < 8; ++i) acc[i] = make_float4(0.f, 0.f, 0.f, 0.f);

#pragma unroll
    for (int c = 0; c < NCH; ++c) {
        const int s0 = (p * NCH + c) << 7;  // window's 128-s base
        if (c > 0) __syncthreads();         // prior window's K reads done

        // fill K (16 glls; wave issues its 4)
#pragma unroll
        for (int jj = 0; jj < 4; ++jj)
            async_cp16(lds + (((w << 2) | jj) << 8), kb + ksrc[jj] + s0);

        // V: the thread's 16-s slice, global->reg (compiler schedules the
        // loads adjacent to use; latency covered by 7-block TLP).
        float4 vv[4][4];
        const float* vbase = vb + ((size_t)(s0 + (sp << 4)) << 5) + e0;
#pragma unroll
        for (int st = 0; st < 4; ++st)
#pragma unroll
            for (int u = 0; u < 4; ++u)
                vv[st][u] = *(const float4*)(vbase + ((st << 2) + u) * DH);

        __syncthreads();                    // K resident (drains vmcnt too)

#pragma unroll
        for (int st = 0; st < 4; ++st) {
            // K: 8 rows x b128 (4 s). chunk c = sp*4+st, read at c ^ dg.
            const int ko = (((sp << 2) + st) ^ dg) << 2;
            float4 kq[8];
#pragma unroll
            for (int i = 0; i < 8; ++i)
                kq[i] = *(const float4*)(lds + ((d0 + i) << 7) + ko);
#pragma unroll
            for (int u = 0; u < 4; ++u) {
                const float4 vu = vv[st][u];
#pragma unroll
                for (int i = 0; i < 8; ++i) {
                    const float ks = (u == 0) ? kq[i].x
                                   : (u == 1) ? kq[i].y
                                   : (u == 2) ? kq[i].z : kq[i].w;
                    fma4(acc[i], ks, vu);
                }
            }
        }
    }

    // butterfly over the wave's two sp-halves (lane ^ 32)
#pragma unroll
    for (int i = 0; i < 8; ++i) {
        acc[i].x += __shfl_xor(acc[i].x, 32);
        acc[i].y += __shfl_xor(acc[i].y, 32);
        acc[i].z += __shfl_xor(acc[i].z, 32);
        acc[i].w += __shfl_xor(acc[i].w, 32);
    }

    __syncthreads();                        // all waves' K reads done: safe to reuse lds
    if (l < 32) {                           // lane l = tile tw, wave-partial
        float* dst = lds + w * 1152 + l * 36;
#pragma unroll
        for (int i = 0; i < 8; ++i) *(float4*)(dst + (i << 2)) = acc[i];
    }
    __syncthreads();

    // final cross-wave sum; thread t owns W[d= t>>3][e4 = (t&7)*4] -> part
    const int fdg = (tid >> 6) & 3;
    const int fi  = (tid >> 3) & 7;
    const int feg = tid & 7;
    const int off = (fdg * 8 + feg) * 36 + (fi << 2);
    float4 r0 = *(const float4*)(lds + off);
    const float4 r1 = *(const float4*)(lds + 1152 + off);
    const float4 r2 = *(const float4*)(lds + 2304 + off);
    const float4 r3 = *(const float4*)(lds + 3456 + off);
    r0.x = (r0.x + r1.x) + (r2.x + r3.x);
    r0.y = (r0.y + r1.y) + (r2.y + r3.y);
    r0.z = (r0.z + r1.z) + (r2.z + r3.z);
    r0.w = (r0.w + r1.w) + (r2.w + r3.w);
    *(float4*)(part + ((size_t)p * (BS * NH) + bh) * 1024 + (tid << 2)) = r0;
}

// ---------------- Kernel B1: reduce partials over p ----------------
// 1024 blocks, one thread per (b,idx), nsp INDEPENDENT coalesced loads.
__global__ __launch_bounds__(256) void reduce_p(const float* __restrict__ part,
                                                float* __restrict__ wts, int nsp) {
    const int gidx = blockIdx.x * 256 + threadIdx.x;   // b*16384 + h*1024+d*32+e
    float s = 0.f;
#pragma unroll 8
    for (int pp = 0; pp < nsp; ++pp)
        s += part[((size_t)pp << 18) + gidx];
    wts[gidx] = s * (1.0f / 64.0f);                    // / sqrt(4096)
}

// ---------------- Kernel B2: softmax over batch axis (in-place on wts) ----------------
__global__ __launch_bounds__(256) void softmax_b(float* __restrict__ wts) {
    const int idx = blockIdx.x * 256 + threadIdx.x;    // 0..16383

    float sc[BS];
#pragma unroll
    for (int b = 0; b < BS; ++b) sc[b] = wts[((size_t)b << 14) + idx];
    float m = sc[0];
#pragma unroll
    for (int b = 1; b < BS; ++b) m = fmaxf(m, sc[b]);
    float sum = 0.f;
#pragma unroll
    for (int b = 0; b < BS; ++b) { sc[b] = __expf(sc[b] - m); sum += sc[b]; }
    const float inv = 1.0f / sum;
#pragma unroll
    for (int b = 0; b < BS; ++b) wts[((size_t)b << 14) + idx] = sc[b] * inv;
}

// ---------------- Kernel C: out = Q @ W ----------------
// 8192 blocks x 256 thr. Q tile staged in LDS (stride 36 -> conflict-free b128 reads),
// W column-block in 128 VGPRs. 1 ds_read_b128 per 16 FMA. ~26us measured.
__global__ __launch_bounds__(256, 2) void qw(const float* __restrict__ q,
                                             const float* __restrict__ wts,
                                             float* __restrict__ out) {
    __shared__ float qs[128 * 36];
    const int blk = blockIdx.x;
    const int bh  = blk >> 5;
    const int lt  = blk & 31;
    const int tid = threadIdx.x;

    const float* qbase = q + ((size_t)bh * LQ + lt * 128) * DH;

#pragma unroll
    for (int pp = 0; pp < 4; ++pp) {
        const int idx = pp * 256 + tid;           // float4 index 0..1023
        const int row = idx >> 3;
        const int c4  = idx & 7;
        const float4 t = *(const float4*)(qbase + idx * 4);
        *(float4*)(qs + row * 36 + c4 * 4) = t;
    }

    const int lsub = tid >> 3;                    // 0..31
    const int e0   = (tid & 7) << 2;

    // wts layout [b][h][d][e]: base = b*16384 + h*1024
    const int b = bh >> 4, h = bh & 15;
    float4 Wf[32];
    const float* wbase = wts + ((size_t)b << 14) + ((size_t)h << 10) + e0;
#pragma unroll
    for (int d = 0; d < 32; ++d) Wf[d] = *(const float4*)(wbase + d * DH);

    __syncthreads();

    float* obase = out + ((size_t)bh * LQ + lt * 128) * DH;

#pragma unroll
    for (int r = 0; r < 4; ++r) {
        const int lr = lsub + r * 32;
        const float* qrow = qs + lr * 36;
        float4 acc = {0, 0, 0, 0};
#pragma unroll
        for (int d4 = 0; d4 < 32; d4 += 4) {
            const float4 qv = *(const float4*)(qrow + d4);
            fma4(acc, qv.x, Wf[d4 + 0]);
            fma4(acc, qv.y, Wf[d4 + 1]);
            fma4(acc, qv.z, Wf[d4 + 2]);
            fma4(acc, qv.w, Wf[d4 + 3]);
        }
        *(float4*)(obase + (size_t)lr * DH + e0) = acc;
    }
}

extern "C" void kernel_launch(void* const* d_in, const int* in_sizes, int n_in,
                              void* d_out, int out_size, void* d_ws, size_t ws_size,
                              hipStream_t stream) {
    const float* q = (const float*)d_in[0];
    const float* k = (const float*)d_in[1];
    const float* v = (const float*)d_in[2];
    float* out  = (float*)d_out;
    float* wts  = out + OUT_ELEMS;          // attn_weights region of d_out
    float* part = (float*)d_ws;

    const size_t need32 = (size_t)32 * 256 * 1024 * 4;   // 33.55 MB of partials
    int nsp;
    if (ws_size >= need32) {
        kv_partial<1><<<256 * 32, 256, 0, stream>>>(k, v, part);
        nsp = 32;
    } else {
        kv_partial<4><<<256 * 8, 256, 0, stream>>>(k, v, part);
        nsp = 8;
    }
    reduce_p<<<(BS * HDE) / 256, 256, 0, stream>>>(part, wts, nsp);
    softmax_b<<<HDE / 256, 256, 0, stream>>>(wts);
    qw<<<BS * NH * (LQ / 128), 256, 0, stream>>>(q, wts, out);
}

// Round 14
// 132.946 us; speedup vs baseline: 2.4473x; 2.4473x over previous
//
#include <hip/hip_runtime.h>

#define BS 16
#define NH 16
#define LQ 4096
#define DH 32

constexpr size_t OUT_ELEMS = (size_t)BS * NH * LQ * DH;   // 33,554,432
constexpr int HDE = NH * DH * DH;           // 16384

// global -> LDS direct copy, 16 B per lane. dst is the WAVE-UNIFORM base;
// HW writes dst + lane*16. src is per-lane.
__device__ __forceinline__ void async_cp16(float* dst, const float* src) {
    __builtin_amdgcn_global_load_lds(
        (const __attribute__((address_space(1))) void*)src,
        (__attribute__((address_space(3))) void*)dst, 16, 0, 0);
}

__device__ __forceinline__ void fma4(float4& a, float s, const float4& v) {
    a.x = fmaf(s, v.x, a.x);
    a.y = fmaf(s, v.y, a.y);
    a.z = fmaf(s, v.z, a.z);
    a.w = fmaf(s, v.w, a.w);
}

// keep-alive: forces the value to be materialized HERE (load issued & waited
// before this point); rule #17. Prevents the compiler legally sinking const
// loads into the compute loop (R12: 4-load bursts -> 4 stalls/block).
__device__ __forceinline__ void pin4(const float4& v) {
    asm volatile("" :: "v"(v.x), "v"(v.y), "v"(v.z), "v"(v.w));
}

// ---------------- Kernel A: partial K@V ----------------
// R12 base (97us) + ONE change: all 16 V float4 pinned before the barrier so
// the block pays ONE latency exposure (20 VMEM in flight: 4 K-gll + 16 V),
// then a pure LDS+FMA compute phase. R13 lesson: never set waves/EU above
// 512/achieved-VGPR -- vv live across barrier => ~150 VGPR => bounds (256,3).
template<int NCH>
__global__ __launch_bounds__(256, 3) void kv_partial(const float* __restrict__ k,
                                                     const float* __restrict__ v,
                                                     float* __restrict__ part) {
    __shared__ float lds[4608];             // K[32][128] swz (4096) / reduce 4x1152
    const int tid = threadIdx.x;
    const int w   = tid >> 6;
    const int l   = tid & 63;
    const int nsplit = 32 / NCH;
    const int p  = blockIdx.x % nsplit;
    const int bh = blockIdx.x / nsplit;

    const int tw = tid & 31;
    const int sp = tid >> 5;                // 0..7
    const int dg = tw >> 3;                 // 0..3
    const int eg = tw & 7;                  // 0..7
    const int d0 = dg << 3;
    const int e0 = eg << 2;

    const float* kb = k + (size_t)bh * DH * LQ;
    const float* vb = v + (size_t)bh * LQ * DH;

    // K gll source constants: instr j covers rows {2j,2j+1}; lane l -> row
    // d = 2j + (l>>5), stored chunk cs = l&31 holds source chunk cs ^ ((j>>2)&3)
    size_t ksrc[4];
#pragma unroll
    for (int jj = 0; jj < 4; ++jj) {
        const int j = (w << 2) | jj;
        const int d = (j << 1) + (l >> 5);
        const int csrc = (l & 31) ^ ((j >> 2) & 3);
        ksrc[jj] = (size_t)d * LQ + (csrc << 2);
    }

    float4 acc[8];
#pragma unroll
    for (int i = 0; i < 8; ++i) acc[i] = make_float4(0.f, 0.f, 0.f, 0.f);

#pragma unroll
    for (int c = 0; c < NCH; ++c) {
        const int s0 = (p * NCH + c) << 7;  // window's 128-s base
        if (c > 0) __syncthreads();         // prior window's K reads done

        // fill K (16 glls; wave issues its 4)
#pragma unroll
        for (int jj = 0; jj < 4; ++jj)
            async_cp16(lds + (((w << 2) | jj) << 8), kb + ksrc[jj] + s0);

        // V: the thread's whole 16-s slice, global->reg, ALL issued now.
        float4 vv[4][4];
        const float* vbase = vb + ((size_t)(s0 + (sp << 4)) << 5) + e0;
#pragma unroll
        for (int st = 0; st < 4; ++st)
#pragma unroll
            for (int u = 0; u < 4; ++u)
                vv[st][u] = *(const float4*)(vbase + ((st << 2) + u) * DH);
        // pin: loads may not sink past here (single stall point, deep MLP)
#pragma unroll
        for (int st = 0; st < 4; ++st)
#pragma unroll
            for (int u = 0; u < 4; ++u) pin4(vv[st][u]);

        __syncthreads();                    // K resident (drains vmcnt too)

#pragma unroll
        for (int st = 0; st < 4; ++st) {
            // K: 8 rows x b128 (4 s). chunk c = sp*4+st, read at c ^ dg.
            const int ko = (((sp << 2) + st) ^ dg) << 2;
            float4 kq[8];
#pragma unroll
            for (int i = 0; i < 8; ++i)
                kq[i] = *(const float4*)(lds + ((d0 + i) << 7) + ko);
#pragma unroll
            for (int u = 0; u < 4; ++u) {
                const float4 vu = vv[st][u];
#pragma unroll
                for (int i = 0; i < 8; ++i) {
                    const float ks = (u == 0) ? kq[i].x
                                   : (u == 1) ? kq[i].y
                                   : (u == 2) ? kq[i].z : kq[i].w;
                    fma4(acc[i], ks, vu);
                }
            }
        }
    }

    // butterfly over the wave's two sp-halves (lane ^ 32)
#pragma unroll
    for (int i = 0; i < 8; ++i) {
        acc[i].x += __shfl_xor(acc[i].x, 32);
        acc[i].y += __shfl_xor(acc[i].y, 32);
        acc[i].z += __shfl_xor(acc[i].z, 32);
        acc[i].w += __shfl_xor(acc[i].w, 32);
    }

    __syncthreads();                        // all waves' K reads done: safe to reuse lds
    if (l < 32) {                           // lane l = tile tw, wave-partial
        float* dst = lds + w * 1152 + l * 36;
#pragma unroll
        for (int i = 0; i < 8; ++i) *(float4*)(dst + (i << 2)) = acc[i];
    }
    __syncthreads();

    // final cross-wave sum; thread t owns W[d= t>>3][e4 = (t&7)*4] -> part
    const int fdg = (tid >> 6) & 3;
    const int fi  = (tid >> 3) & 7;
    const int feg = tid & 7;
    const int off = (fdg * 8 + feg) * 36 + (fi << 2);
    float4 r0 = *(const float4*)(lds + off);
    const float4 r1 = *(const float4*)(lds + 1152 + off);
    const float4 r2 = *(const float4*)(lds + 2304 + off);
    const float4 r3 = *(const float4*)(lds + 3456 + off);
    r0.x = (r0.x + r1.x) + (r2.x + r3.x);
    r0.y = (r0.y + r1.y) + (r2.y + r3.y);
    r0.z = (r0.z + r1.z) + (r2.z + r3.z);
    r0.w = (r0.w + r1.w) + (r2.w + r3.w);
    *(float4*)(part + ((size_t)p * (BS * NH) + bh) * 1024 + (tid << 2)) = r0;
}

// ---------------- Kernel B1: reduce partials over p ----------------
// 1024 blocks, one thread per (b,idx), nsp INDEPENDENT coalesced loads.
__global__ __launch_bounds__(256) void reduce_p(const float* __restrict__ part,
                                                float* __restrict__ wts, int nsp) {
    const int gidx = blockIdx.x * 256 + threadIdx.x;   // b*16384 + h*1024+d*32+e
    float s = 0.f;
#pragma unroll 8
    for (int pp = 0; pp < nsp; ++pp)
        s += part[((size_t)pp << 18) + gidx];
    wts[gidx] = s * (1.0f / 64.0f);                    // / sqrt(4096)
}

// ---------------- Kernel B2: softmax over batch axis (in-place on wts) ----------------
__global__ __launch_bounds__(256) void softmax_b(float* __restrict__ wts) {
    const int idx = blockIdx.x * 256 + threadIdx.x;    // 0..16383

    float sc[BS];
#pragma unroll
    for (int b = 0; b < BS; ++b) sc[b] = wts[((size_t)b << 14) + idx];
    float m = sc[0];
#pragma unroll
    for (int b = 1; b < BS; ++b) m = fmaxf(m, sc[b]);
    float sum = 0.f;
#pragma unroll
    for (int b = 0; b < BS; ++b) { sc[b] = __expf(sc[b] - m); sum += sc[b]; }
    const float inv = 1.0f / sum;
#pragma unroll
    for (int b = 0; b < BS; ++b) wts[((size_t)b << 14) + idx] = sc[b] * inv;
}

// ---------------- Kernel C: out = Q @ W ----------------
// 8192 blocks x 256 thr. Q tile staged in LDS (stride 36 -> conflict-free b128 reads),
// W column-block in 128 VGPRs. 1 ds_read_b128 per 16 FMA. ~26us measured.
__global__ __launch_bounds__(256, 2) void qw(const float* __restrict__ q,
                                             const float* __restrict__ wts,
                                             float* __restrict__ out) {
    __shared__ float qs[128 * 36];
    const int blk = blockIdx.x;
    const int bh  = blk >> 5;
    const int lt  = blk & 31;
    const int tid = threadIdx.x;

    const float* qbase = q + ((size_t)bh * LQ + lt * 128) * DH;

#pragma unroll
    for (int pp = 0; pp < 4; ++pp) {
        const int idx = pp * 256 + tid;           // float4 index 0..1023
        const int row = idx >> 3;
        const int c4  = idx & 7;
        const float4 t = *(const float4*)(qbase + idx * 4);
        *(float4*)(qs + row * 36 + c4 * 4) = t;
    }

    const int lsub = tid >> 3;                    // 0..31
    const int e0   = (tid & 7) << 2;

    // wts layout [b][h][d][e]: base = b*16384 + h*1024
    const int b = bh >> 4, h = bh & 15;
    float4 Wf[32];
    const float* wbase = wts + ((size_t)b << 14) + ((size_t)h << 10) + e0;
#pragma unroll
    for (int d = 0; d < 32; ++d) Wf[d] = *(const float4*)(wbase + d * DH);

    __syncthreads();

    float* obase = out + ((size_t)bh * LQ + lt * 128) * DH;

#pragma unroll
    for (int r = 0; r < 4; ++r) {
        const int lr = lsub + r * 32;
        const float* qrow = qs + lr * 36;
        float4 acc = {0, 0, 0, 0};
#pragma unroll
        for (int d4 = 0; d4 < 32; d4 += 4) {
            const float4 qv = *(const float4*)(qrow + d4);
            fma4(acc, qv.x, Wf[d4 + 0]);
            fma4(acc, qv.y, Wf[d4 + 1]);
            fma4(acc, qv.z, Wf[d4 + 2]);
            fma4(acc, qv.w, Wf[d4 + 3]);
        }
        *(float4*)(obase + (size_t)lr * DH + e0) = acc;
    }
}

extern "C" void kernel_launch(void* const* d_in, const int* in_sizes, int n_in,
                              void* d_out, int out_size, void* d_ws, size_t ws_size,
                              hipStream_t stream) {
    const float* q = (const float*)d_in[0];
    const float* k = (const float*)d_in[1];
    const float* v = (const float*)d_in[2];
    float* out  = (float*)d_out;
    float* wts  = out + OUT_ELEMS;          // attn_weights region of d_out
    float* part = (float*)d_ws;

    const size_t need32 = (size_t)32 * 256 * 1024 * 4;   // 33.55 MB of partials
    int nsp;
    if (ws_size >= need32) {
        kv_partial<1><<<256 * 32, 256, 0, stream>>>(k, v, part);
        nsp = 32;
    } else {
        kv_partial<4><<<256 * 8, 256, 0, stream>>>(k, v, part);
        nsp = 8;
    }
    reduce_p<<<(BS * HDE) / 256, 256, 0, stream>>>(part, wts, nsp);
    softmax_b<<<HDE / 256, 256, 0, stream>>>(wts);
    qw<<<BS * NH * (LQ / 128), 256, 0, stream>>>(q, wts, out);
}